// Round 4
// baseline (701.002 us; speedup 1.0000x reference)
//
#include <hip/hip_runtime.h>
#include <math.h>

#define EMBED  1024
#define HIDDEN 1024
#define VOCAB  32000
#define TSTEPS 64
#define NBLK   256   // 1 block per CU, all co-resident (persistent kernel)

// ---------------------------------------------------------------------------
// ONE fused persistent kernel, regular launch (R3 post-mortem: ~300 us of the
// 651 us total was launch machinery — cooperative launch + 5 dispatches +
// memset — not kernel time; non-lstm portion was constant 415-450 us across
// three different GEMM implementations).
//
// Phase 1: each block computes the 16 Xg columns {g*1024+4b+w} its own LSTM
//          phase consumes (block-local -> no cross-block sync needed), with
//          xs gathered on the fly from embed_table/features. Results -> LDS.
// Phase 2: sequential LSTM with data-flow h exchange: packed (tag=t+1, h)
//          u64 agent-scope atomics in hs_pk[64][1024]; step t polls row t-1
//          (t=0 uses zeros). Tags 1..64 never match 0xAA poison -> no memset.
// Phase 3: logits. Blocks 0..249 own 128 vocab rows each; hs chunks staged
//          from hs_pk by tag-poll (tolerates +-1-step stragglers); fc_W
//          staged coalesced; 4t x 8v register tile, v interleaved (tv+16j)
//          so w_s3 b128 reads are 2-way bank aliased = free at stride 68.
//
// Co-residency w/o cooperative launch: 256 blocks of 256 thr, 64.6 KB LDS,
// ~100 VGPR -> 1+ block/CU fits; 256 blocks <= 256 CUs -> all dispatched
// before any spin can block progress. Spin uses s_sleep.
// ---------------------------------------------------------------------------
__global__ __launch_bounds__(256, 1) void decoder_fused(
    const int*   __restrict__ caps,
    const float* __restrict__ feat,
    const float* __restrict__ table,
    const float* __restrict__ Wih,
    const float* __restrict__ Whh,
    const float* __restrict__ bih,
    const float* __restrict__ bhh,
    const float* __restrict__ fcW,
    const float* __restrict__ fcb,
    unsigned long long* hs_pk,   // [64][1024] packed (tag,value)
    float* __restrict__ out)
{
    // LDS arena reused across phases:
    //   phase 1: xs_s[64][132] (33792 B) + w16[16][132] (8448 B) = 42240 B
    //   phase 3: hs_s[64][68] (17408 B) + w_s3[128][68] (34816 B) = 52224 B
    __shared__ __align__(16) char arena[52224];
    __shared__ float xg_s[TSTEPS][16];   // persists phase1 -> phase2
    __shared__ float h_s[2][HIDDEN];     // phase2 double buffer
    __shared__ int   caps_s[TSTEPS];

    int tid = threadIdx.x;
    int b   = blockIdx.x;

    // ---- phase-2 weight prefetch issued first (hides HBM under phase 1)
    int lane = tid & 63;
    int wv   = tid >> 6;          // output sub-index 0..3 (one per wave)
    int g    = lane >> 4;         // gate index 0..3 (i,f,g,o)
    int c16  = lane & 15;
    int hj   = 4 * b + wv;
    const float4* wrow = (const float4*)(Whh + ((size_t)g * HIDDEN + hj) * HIDDEN);
    float4 wreg[16];
#pragma unroll
    for (int k = 0; k < 16; ++k) wreg[k] = wrow[c16 + 16 * k];

    if (tid < TSTEPS) caps_s[tid] = caps[tid];

    // ================= phase 1: xg_s[t][r] for this block's 16 columns ====
    float (*xs_s)[132] = (float (*)[132])arena;            // 64 x 132
    float (*w16)[132]  = (float (*)[132])(arena + 33792);  // 16 x 132
    int jl = tid & 15;            // r = g*4+w
    int tg = tid >> 4;            // 16 groups x 4 timesteps
    float acc4[4] = {0.f, 0.f, 0.f, 0.f};
    __syncthreads();              // caps_s visible

    for (int c = 0; c < 8; ++c) {
        __syncthreads();
        // stage xs chunk [64][128]: gather embed rows, coalesced float4
        for (int idx = tid; idx < 64 * 32; idx += 256) {
            int r = idx >> 5, f4 = idx & 31;
            const float* src = (r == 0)
                ? (feat + c * 128)
                : (table + (size_t)caps_s[r - 1] * EMBED + c * 128);
            *((float4*)&xs_s[r][f4 * 4]) = ((const float4*)src)[f4];
        }
        // stage the block's 16 W_ih row-chunks (row g*1024 + 4b + w)
        for (int idx = tid; idx < 16 * 32; idx += 256) {
            int r = idx >> 5, f4 = idx & 31;
            int jr = (r >> 2) * HIDDEN + 4 * b + (r & 3);
            *((float4*)&w16[r][f4 * 4]) =
                ((const float4*)(Wih + (size_t)jr * EMBED + c * 128))[f4];
        }
        __syncthreads();
        for (int f4 = 0; f4 < 32; ++f4) {
            float4 w = *((const float4*)&w16[jl][f4 * 4]);
#pragma unroll
            for (int k = 0; k < 4; ++k) {
                const float* xr = &xs_s[tg * 4 + k][f4 * 4];
                acc4[k] += w.x * xr[0] + w.y * xr[1] + w.z * xr[2] + w.w * xr[3];
            }
        }
    }
    {
        int jrow = (jl >> 2) * HIDDEN + 4 * b + (jl & 3);
        float bias = bih[jrow] + bhh[jrow];
#pragma unroll
        for (int k = 0; k < 4; ++k) xg_s[tg * 4 + k][jl] = acc4[k] + bias;
    }
    __syncthreads();

    // ================= phase 2: sequential LSTM =================
    float cstate = 0.f;           // live in lane 0 of each wave only
    for (int t = 0; t < TSTEPS; ++t) {
        float* dst = h_s[t & 1];
        if (t == 0) {
            for (int i = tid; i < HIDDEN; i += 256) dst[i] = 0.f;
        } else {
            const unsigned long long* hsrc = hs_pk + (size_t)(t - 1) * HIDDEN;
            unsigned want = (unsigned)t;   // producer stored tag (t-1)+1 = t
            unsigned long long x0 = 0, x1 = 0, x2 = 0, x3 = 0;
            int need = 0xF;
            do {
                if (need & 1) {
                    x0 = __hip_atomic_load(hsrc + tid, __ATOMIC_RELAXED,
                                           __HIP_MEMORY_SCOPE_AGENT);
                    if ((unsigned)(x0 >> 32) == want) need &= ~1;
                }
                if (need & 2) {
                    x1 = __hip_atomic_load(hsrc + tid + 256, __ATOMIC_RELAXED,
                                           __HIP_MEMORY_SCOPE_AGENT);
                    if ((unsigned)(x1 >> 32) == want) need &= ~2;
                }
                if (need & 4) {
                    x2 = __hip_atomic_load(hsrc + tid + 512, __ATOMIC_RELAXED,
                                           __HIP_MEMORY_SCOPE_AGENT);
                    if ((unsigned)(x2 >> 32) == want) need &= ~4;
                }
                if (need & 8) {
                    x3 = __hip_atomic_load(hsrc + tid + 768, __ATOMIC_RELAXED,
                                           __HIP_MEMORY_SCOPE_AGENT);
                    if ((unsigned)(x3 >> 32) == want) need &= ~8;
                }
                if (need) __builtin_amdgcn_s_sleep(1);
            } while (need);
            dst[tid]       = __uint_as_float((unsigned)x0);
            dst[tid + 256] = __uint_as_float((unsigned)x1);
            dst[tid + 512] = __uint_as_float((unsigned)x2);
            dst[tid + 768] = __uint_as_float((unsigned)x3);
        }
        __syncthreads();

        float4 a = {0.f, 0.f, 0.f, 0.f};
#pragma unroll
        for (int k = 0; k < 16; ++k) {
            float4 w = wreg[k];
            const float* hv = &dst[(c16 + 16 * k) * 4];
            a.x += w.x * hv[0];
            a.y += w.y * hv[1];
            a.z += w.z * hv[2];
            a.w += w.w * hv[3];
        }
        float sum = (a.x + a.y) + (a.z + a.w);
        sum += __shfl_xor(sum, 1);
        sum += __shfl_xor(sum, 2);
        sum += __shfl_xor(sum, 4);
        sum += __shfl_xor(sum, 8);
        float s0 = __shfl(sum, 0);
        float s1 = __shfl(sum, 16);
        float s2 = __shfl(sum, 32);
        float s3 = __shfl(sum, 48);

        if (lane == 0) {
            float gi = s0 + xg_s[t][wv];
            float gf = s1 + xg_s[t][4 + wv];
            float gg = s2 + xg_s[t][8 + wv];
            float go = s3 + xg_s[t][12 + wv];
            float i_ = 1.f / (1.f + expf(-gi));
            float f_ = 1.f / (1.f + expf(-gf));
            float g_ = tanhf(gg);
            float o_ = 1.f / (1.f + expf(-go));
            cstate = f_ * cstate + i_ * g_;
            float hv = o_ * tanhf(cstate);
            unsigned long long pk =
                ((unsigned long long)(unsigned)(t + 1) << 32) |
                (unsigned long long)__float_as_uint(hv);
            __hip_atomic_store(hs_pk + (size_t)t * HIDDEN + hj, pk,
                               __ATOMIC_RELAXED, __HIP_MEMORY_SCOPE_AGENT);
        }
        // no trailing barrier: h_s double-buffered, xg_s read-only
    }
    __syncthreads();

    // ================= phase 3: logits for 128 vocab rows =================
    if (b >= 250) return;         // 250 * 128 = 32000
    float (*hs_s)[68]  = (float (*)[68])arena;             // 64 x 68
    float (*w_s3)[68]  = (float (*)[68])(arena + 17408);   // 128 x 68
    int tv = tid & 15;            // vocab lane; owns rows v0 + tv + 16*j
    int tq = tid >> 4;            // timestep quad: rows tq*4 .. tq*4+3
    int v0 = b * 128;
    float acc[4][8];
#pragma unroll
    for (int i = 0; i < 4; ++i)
#pragma unroll
        for (int j = 0; j < 8; ++j) acc[i][j] = 0.f;

    for (int kc = 0; kc < 16; ++kc) {   // K in chunks of 64
        __syncthreads();
        // stage hs chunk [64][64] from hs_pk with tag-poll (straggler-safe)
        for (int idx = tid; idx < 64 * 64; idx += 256) {
            int t = idx >> 6, j = idx & 63;
            unsigned want = (unsigned)(t + 1);
            unsigned long long x;
            for (;;) {
                x = __hip_atomic_load(hs_pk + (size_t)t * HIDDEN + kc * 64 + j,
                                      __ATOMIC_RELAXED, __HIP_MEMORY_SCOPE_AGENT);
                if ((unsigned)(x >> 32) == want) break;
                __builtin_amdgcn_s_sleep(1);
            }
            hs_s[t][j] = __uint_as_float((unsigned)x);
        }
        // stage fc_W chunk [128][64] — coalesced 256B bursts per row
        for (int idx = tid; idx < 128 * 16; idx += 256) {
            int r = idx >> 4, f4 = idx & 15;
            *((float4*)&w_s3[r][f4 * 4]) =
                ((const float4*)(fcW + (size_t)(v0 + r) * HIDDEN + kc * 64))[f4];
        }
        __syncthreads();
        for (int q = 0; q < 16; ++q) {
            float4 hv4[4];
#pragma unroll
            for (int i = 0; i < 4; ++i)
                hv4[i] = *((const float4*)&hs_s[tq * 4 + i][q * 4]);  // broadcast
#pragma unroll
            for (int j = 0; j < 8; ++j) {
                float4 w4 = *((const float4*)&w_s3[tv + 16 * j][q * 4]); // 2-way, free
#pragma unroll
                for (int i = 0; i < 4; ++i) {
                    acc[i][j] += w4.x * hv4[i].x + w4.y * hv4[i].y +
                                 w4.z * hv4[i].z + w4.w * hv4[i].w;
                }
            }
        }
    }
    float bj[8];
#pragma unroll
    for (int j = 0; j < 8; ++j) bj[j] = fcb[v0 + tv + 16 * j];
#pragma unroll
    for (int i = 0; i < 4; ++i)
#pragma unroll
        for (int j = 0; j < 8; ++j)
            out[(size_t)(tq * 4 + i) * VOCAB + v0 + tv + 16 * j] = acc[i][j] + bj[j];
}

// ---------------------------------------------------------------------------
extern "C" void kernel_launch(void* const* d_in, const int* in_sizes, int n_in,
                              void* d_out, int out_size, void* d_ws, size_t ws_size,
                              hipStream_t stream) {
    const int*   caps  = (const int*)  d_in[0];
    const float* feat  = (const float*)d_in[1];
    const float* table = (const float*)d_in[2];
    const float* Wih   = (const float*)d_in[3];
    const float* Whh   = (const float*)d_in[4];
    const float* bih   = (const float*)d_in[5];
    const float* bhh   = (const float*)d_in[6];
    const float* fcW   = (const float*)d_in[7];
    const float* fcb   = (const float*)d_in[8];
    float* out = (float*)d_out;

    // Workspace: only hs_pk [64][1024] u64 (512 KB). No memset needed:
    // 0xAA poison never matches a valid tag (1..64), so every poll waits
    // for a fresh write from this call.
    unsigned long long* hs_pk = (unsigned long long*)d_ws;

    decoder_fused<<<NBLK, 256, 0, stream>>>(caps, feat, table, Wih, Whh,
                                            bih, bhh, fcW, fcb, hs_pk, out);
}